// Round 4
// baseline (988.592 us; speedup 1.0000x reference)
//
#include <hip/hip_runtime.h>

typedef unsigned short u16;
typedef unsigned int u32;
typedef short bf16x8 __attribute__((ext_vector_type(8)));
typedef float f32x4 __attribute__((ext_vector_type(4)));

__device__ __forceinline__ float bf2f(u16 u) {
  u32 x = ((u32)u) << 16;
  float f;
  __builtin_memcpy(&f, &x, 4);
  return f;
}
__device__ __forceinline__ u16 f2bf(float f) {
  u32 x;
  __builtin_memcpy(&x, &f, 4);
  u32 r = x + 0x7FFFu + ((x >> 16) & 1u);
  return (u16)(r >> 16);
}
// pack two fp32 -> bf16x2 (round-to-nearest-half-up): 2 adds + v_perm
__device__ __forceinline__ u32 pack2(float f0, float f1) {
  u32 a, b;
  __builtin_memcpy(&a, &f0, 4);
  __builtin_memcpy(&b, &f1, 4);
  a += 0x8000u;
  b += 0x8000u;
  return __builtin_amdgcn_perm(b, a, 0x07060302);
}
// pack two fp32 -> bf16x2 in ONE VALU op (RTNE): v_cvt_pk_bf16_f32 (gfx950)
__device__ __forceinline__ u32 cvtpk(float f0, float f1) {
  u32 r;
  asm("v_cvt_pk_bf16_f32 %0, %1, %2" : "=v"(r) : "v"(f0), "v"(f1));
  return r;
}

// ---------------- geometry ----------------
// levels: W {256,128,64,32,16} H {160,80,40,20,10}; padded (W+2)x(H+2) NHWC bf16
// padded pixel bases {0, 41796, 52456, 55228, 55976}; total 56192 px
// per-tower activation stride = 56192*256 = 14,385,152 u16 elements

// ---------------- weight conversion ----------------
// tower layout per conv (A-fragment order): [mo(2)][kt(72)][wm(2)][mi(4)][lane(64)][j(8)]
//   kt = ch*9 + ti, ti = dx*3+dy (dx-major for B row caching)
// head layout: [kt(72)][mi(MI)][lane(64)][j(8)] per head; cls MT=96 (80+ctr+pad),
//   reg MT=16 (4+pad), msk MT=48 (36+pad); offsets 0 / 221184 / 258048.
__global__ void convert_weights(const float* __restrict__ cw, const float* __restrict__ rw,
                                const float* __restrict__ mw, const float* __restrict__ pc,
                                const float* __restrict__ pr, const float* __restrict__ pm,
                                const float* __restrict__ pt, u16* __restrict__ dst) {
  int e = blockIdx.x * 256 + threadIdx.x;
  if (e >= 7446528) return;
  float v = 0.f;
  if (e < 7077888) {
    int conv = e / 589824, r = e % 589824;
    int mo = r / 294912;
    int r2 = r - mo * 294912;
    int kt = r2 >> 12;
    int r3 = r2 & 4095;
    int wm = r3 >> 11;
    int mi = (r3 >> 9) & 3;
    int l = (r3 >> 3) & 63;
    int j = r3 & 7;
    int ch = kt / 9, ti = kt - ch * 9;
    int dxs = ti / 3, dys = ti - dxs * 3;
    int tap = dys * 3 + dxs;
    int o = mo * 128 + wm * 64 + mi * 16 + (l & 15);
    int c = ch * 32 + (l >> 4) * 8 + j;
    const float* s = (conv < 4) ? cw : (conv < 8) ? rw : mw;
    int si = conv & 3;
    v = s[((si * 256 + o) * 256 + c) * 9 + tap];
  } else {
    int e2 = e - 7077888;
    int kt, r2, mi, mtsel;
    const float* src = nullptr;
    int olim = 0;
    bool ctr = false;
    if (e2 < 221184) {        // cls MT=96
      kt = e2 / 3072; r2 = e2 % 3072; mi = r2 / 512; r2 %= 512;
      src = pc; olim = 80; ctr = true;
    } else if (e2 < 258048) { // reg MT=16
      int e3 = e2 - 221184;
      kt = e3 / 512; r2 = e3 % 512; mi = 0;
      src = pr; olim = 4;
    } else {                  // msk MT=48
      int e3 = e2 - 258048;
      kt = e3 / 1536; r2 = e3 % 1536; mi = r2 / 512; r2 %= 512;
      src = pm; olim = 36;
    }
    int l = r2 >> 3, j = r2 & 7;
    int ch = kt / 9, ti = kt - ch * 9;
    int dxs = ti / 3, dys = ti - dxs * 3;
    int tap = dys * 3 + dxs;
    int o = mi * 16 + (l & 15);
    int c = ch * 32 + (l >> 4) * 8 + j;
    if (o < olim) v = src[(o * 256 + c) * 9 + tap];
    else if (ctr && o == 80) v = pt[c * 9 + tap];
    (void)mtsel;
  }
  dst[e] = f2bf(v);
}

// ---------------- halo zero: clear 1-px border of padded buffers ----------------
__global__ void halo_zero(u16* __restrict__ X, u16* __restrict__ Y, long ACT, int ntw) {
  int i = blockIdx.x * 256 + threadIdx.x;
  int rep = i / 26112;         // 1632*16
  int j = i - rep * 26112;
  if (rep >= 2 * ntw) return;
  int hp = j >> 4, sub = j & 15;
  int Wp, Hp, pxb, h;
  if (hp < 836)       { Wp = 258; Hp = 162; pxb = 0;     h = hp; }
  else if (hp < 1256) { Wp = 130; Hp = 82;  pxb = 41796; h = hp - 836; }
  else if (hp < 1468) { Wp = 66;  Hp = 42;  pxb = 52456; h = hp - 1256; }
  else if (hp < 1576) { Wp = 34;  Hp = 22;  pxb = 55228; h = hp - 1468; }
  else                { Wp = 18;  Hp = 12;  pxb = 55976; h = hp - 1576; }
  int y, x;
  if (h < Wp)          { y = 0;      x = h; }
  else if (h < 2 * Wp) { y = Hp - 1; x = h - Wp; }
  else {
    int rr = h - 2 * Wp;
    y = 1 + (rr >> 1);
    x = (rr & 1) ? (Wp - 1) : 0;
  }
  u16* buf = (rep < ntw) ? (X + rep * ACT) : (Y + (rep - ntw) * ACT);
  long adr = (long)(pxb + y * Wp + x) * 256 + sub * 16;
  uint4 z = {0, 0, 0, 0};
  *(uint4*)(buf + adr) = z;
  *(uint4*)(buf + adr + 8) = z;
}

// ---------------- feat NCHW fp32 -> padded NHWC bf16 ----------------
__global__ void feat_to_nhwc(const float* __restrict__ f0, const float* __restrict__ f1,
                             const float* __restrict__ f2, const float* __restrict__ f3,
                             const float* __restrict__ f4, u16* __restrict__ dst,
                             long tstride, int nrep) {
  __shared__ float lds[64 * 65];
  int bx = blockIdx.x;
  int tile = bx >> 2, c0 = (bx & 3) * 64;
  int tl, sh, pxb, npx;
  const float* src;
  if (tile < 640)      { tl = tile;       sh = 8; pxb = 0;     npx = 40960; src = f0; }
  else if (tile < 800) { tl = tile - 640; sh = 7; pxb = 41796; npx = 10240; src = f1; }
  else if (tile < 840) { tl = tile - 800; sh = 6; pxb = 52456; npx = 2560;  src = f2; }
  else if (tile < 850) { tl = tile - 840; sh = 5; pxb = 55228; npx = 640;   src = f3; }
  else                 { tl = tile - 850; sh = 4; pxb = 55976; npx = 160;   src = f4; }
  int W = 1 << sh, Wp = W + 2;
  int px0 = tl * 64;
  int t = threadIdx.x;
  {
    int cc = (t >> 6) * 16, px = t & 63;
    bool ok = (px0 + px) < npx;
#pragma unroll
    for (int j = 0; j < 16; ++j) {
      float v = ok ? src[(c0 + cc + j) * npx + px0 + px] : 0.f;
      lds[(cc + j) * 65 + px] = v;
    }
  }
  __syncthreads();
  {
    int px = t >> 2, cL = (t & 3) * 16;
    int pxi = px0 + px;
    if (pxi < npx) {
      int y = pxi >> sh, x = pxi & (W - 1);
      u32 w[8];
#pragma unroll
      for (int j = 0; j < 8; ++j)
        w[j] = pack2(lds[(cL + 2 * j) * 65 + px], lds[(cL + 2 * j + 1) * 65 + px]);
      long adr = (long)(pxb + (y + 1) * Wp + (x + 1)) * 256 + c0 + cL;
      uint4 v0 = {w[0], w[1], w[2], w[3]}, v1 = {w[4], w[5], w[6], w[7]};
      for (int r = 0; r < nrep; ++r) {
        *(uint4*)(dst + r * tstride + adr) = v0;
        *(uint4*)(dst + r * tstride + adr + 8) = v1;
      }
    }
  }
}

// ---------------- finalize GN stats -> per-channel (scale, bias) ----------------
__global__ void finalize_stats(const float* __restrict__ stats, int st_ts,
                               const float* __restrict__ g0, const float* __restrict__ g1,
                               const float* __restrict__ g2, const float* __restrict__ b0,
                               const float* __restrict__ b1, const float* __restrict__ b2,
                               float* __restrict__ scaleb, int sb_ts, int ntw) {
  int i = blockIdx.x * 256 + threadIdx.x;
  if (i >= ntw * 1280) return;
  int tw = i / 1280, r = i - tw * 1280, lvl = r >> 8, c = r & 255, g = c >> 3;
  float cnt = (lvl == 0) ? 327680.f : (lvl == 1) ? 81920.f
              : (lvl == 2) ? 20480.f : (lvl == 3) ? 5120.f : 1280.f;
  float s1 = stats[tw * st_ts + (lvl * 32 + g) * 2];
  float s2 = stats[tw * st_ts + (lvl * 32 + g) * 2 + 1];
  float mean = s1 / cnt;
  float var = s2 / cnt - mean * mean;
  float inv = rsqrtf(fmaxf(var, 0.f) + 1e-5f);
  const float* ga = (tw == 0) ? g0 : (tw == 1) ? g1 : g2;
  const float* be = (tw == 0) ? b0 : (tw == 1) ? b1 : b2;
  float sc = inv * ga[c];
  scaleb[(long)tw * sb_ts + (lvl * 256 + c) * 2] = sc;
  scaleb[(long)tw * sb_ts + (lvl * 256 + c) * 2 + 1] = be[c] - mean * sc;
}

// ---------------- tower conv: 256->256 3x3, bf16 MFMA implicit GEMM ----------------
// 128 o x 128 px block, 4 waves, 4x4 frags. A global->registers (fragment order),
// DEPTH-2 prefetch via 3-slot rotation (kt%3 == ti%3, all indices compile-time).
// B: plane-split LDS tile, double-buffered across ch-steps (1 barrier/step).
// breg (HBM activation prefetch) issued inside ti=0 (after first A-group issue) to
// defer the in-order-vmcnt force-drain to ti=3. setprio(1) around MFMA clusters.
// Staging GN math: v_cvt_pk_bf16_f32 pack (1 op/pair) + packed-u32 border selects.
__global__ __launch_bounds__(256, 3) void conv_tower(
    const u16* __restrict__ Xn, long in_ts, const u16* __restrict__ Wt, long wt_ts,
    u16* __restrict__ Yraw, long out_ts, float* __restrict__ stats, int st_ts,
    const float* __restrict__ scaleb, int sb_ts, int do_gn) {
  __shared__ __align__(16) u16 Btile[11520];  // 2 x (4 planes x 180 px x 8 ch)
  __shared__ float shSB[512];                 // (scale,bias) per channel
  __shared__ float sred[32];
  int bx = blockIdx.x;
  int tw = bx / 856, r856 = bx - tw * 856;
  Xn += tw * in_ts; Wt += tw * wt_ts; Yraw += tw * out_ts; stats += tw * st_ts;
  int tile = r856 >> 1, mo = r856 & 1;
  int tloc, W, H, SX, pxb, lvl;
  if (tile < 320)      { lvl = 0; tloc = tile;       W = 256; H = 160; SX = 4; pxb = 0; }
  else if (tile < 400) { lvl = 1; tloc = tile - 320; W = 128; H = 80;  SX = 3; pxb = 41796; }
  else if (tile < 420) { lvl = 2; tloc = tile - 400; W = 64;  H = 40;  SX = 2; pxb = 52456; }
  else if (tile < 426) { lvl = 3; tloc = tile - 420; W = 32;  H = 20;  SX = 1; pxb = 55228; }
  else                 { lvl = 4; tloc = tile - 426; W = 16;  H = 10;  SX = 0; pxb = 55976; }
  int Wp = W + 2;
  int ty = tloc >> SX, txi = tloc & ((1 << SX) - 1);
  int y0 = ty * 8, x0 = txi * 16;
  int t = threadIdx.x, lane = t & 63, wave = t >> 6;
  int wm = wave >> 1, wn = wave & 1;
  int quad = lane >> 4, col = lane & 15;
  const u16* Xbase = Xn + (long)(pxb + y0 * Wp + x0) * 256;
  const u16* Wb = Wt + (long)mo * 294912 + wm * 2048 + (long)lane * 8;
  int bcol = quad * 1440 + wn * 576 + col * 8;
  if (do_gn) {
    float2 sv = *(const float2*)(scaleb + (long)tw * sb_ts + (lvl * 256 + t) * 2);
    *(float2*)(&shSB[t * 2]) = sv;
  }
  const u16* Pptr[3];
  int Lo[3], Cb[3];
  bool Uok[3], Keep[3];
#pragma unroll
  for (int i = 0; i < 3; ++i) {
    int u = t + i * 256;
    Uok[i] = u < 720;
    int q = u & 3, p = u >> 2;
    int py = p / 18, px = p - py * 18;
    Pptr[i] = Xbase + (long)(py * Wp + px) * 256 + q * 8;
    Lo[i] = q * 1440 + p * 8;
    Cb[i] = q * 8;
    int yg = y0 + py, xg = x0 + px;
    Keep[i] = (yg >= 1) && (yg <= H) && (xg >= 1) && (xg <= W);
  }
  uint4 breg[3];
#pragma unroll
  for (int i = 0; i < 3; ++i)
    if (Uok[i]) breg[i] = *(const uint4*)(Pptr[i]);
  // 3-slot A rotation: slot[kt%3]; since kt = ch*9+ti and 9%3==0, slot == ti%3.
  bf16x8 areg[3][4];
#pragma unroll
  for (int mi = 0; mi < 4; ++mi) areg[0][mi] = *(const bf16x8*)(Wb + mi * 512);
#pragma unroll
  for (int mi = 0; mi < 4; ++mi) areg[1][mi] = *(const bf16x8*)(Wb + 4096 + mi * 512);
  f32x4 acc[4][4] = {};
  // stage breg (channel group cc) into Btile[bo..] with fused GN+ReLU
  auto stage = [&](int bo, int cc) {
#pragma unroll
    for (int i = 0; i < 3; ++i) {
      if (Uok[i]) {
        uint4 v = breg[i];
        if (do_gn) {
          int cb2 = (Cb[i] + cc * 32) * 2;
          float4 s01 = *(const float4*)(&shSB[cb2]);
          float4 s23 = *(const float4*)(&shSB[cb2 + 4]);
          float4 s45 = *(const float4*)(&shSB[cb2 + 8]);
          float4 s67 = *(const float4*)(&shSB[cb2 + 12]);
          u32 wv[4] = {v.x, v.y, v.z, v.w};
          float sc[8] = {s01.x, s01.z, s23.x, s23.z, s45.x, s45.z, s67.x, s67.z};
          float bi[8] = {s01.y, s01.w, s23.y, s23.w, s45.y, s45.w, s67.y, s67.w};
          bool kp = Keep[i];
          u32 ow[4];
#pragma unroll
          for (int jj = 0; jj < 4; ++jj) {
            u32 lo32 = wv[jj] << 16, hi32 = wv[jj] & 0xffff0000u;
            float flo, fhi;
            __builtin_memcpy(&flo, &lo32, 4);
            __builtin_memcpy(&fhi, &hi32, 4);
            float f0 = fmaxf(flo * sc[2 * jj] + bi[2 * jj], 0.f);
            float f1 = fmaxf(fhi * sc[2 * jj + 1] + bi[2 * jj + 1], 0.f);
            ow[jj] = cvtpk(f0, f1);
          }
          v.x = kp ? ow[0] : 0u;
          v.y = kp ? ow[1] : 0u;
          v.z = kp ? ow[2] : 0u;
          v.w = kp ? ow[3] : 0u;
        }
        *(uint4*)(Btile + bo + Lo[i]) = v;
      }
    }
  };
  __syncthreads();  // shSB visible before prologue staging
  stage(0, 0);      // prologue: stage ch0 -> buf0
#pragma unroll
  for (int i = 0; i < 3; ++i)
    if (Uok[i]) breg[i] = *(const uint4*)(Pptr[i] + 32);  // prefetch ch1
  __syncthreads();  // buf0 visible
  for (int ch = 0; ch < 8; ++ch) {
    int bb = (ch & 1) * 5760;
    if (ch < 7) stage(5760 - bb, ch + 1);  // overlaps with MFMA below (other buffer)
    bf16x8 brow[6];
#pragma unroll
    for (int ti = 0; ti < 9; ++ti) {
      int kt = ch * 9 + ti;
      int dxq = ti / 3, dyq = ti - dxq * 3;
      if (dyq == 0) {
#pragma unroll
        for (int r = 0; r < 6; ++r)
          brow[r] = *(const bf16x8*)(Btile + bb + bcol + r * 144 + dxq * 8);
      }
      {  // prefetch A(kt+2) into slot (ti+2)%3; kt=70/71 over-read stays inside wts
        const u16* wn_ = Wb + (long)(kt + 2) * 4096;
#pragma unroll
        for (int mi = 0; mi < 4; ++mi)
          areg[(ti + 2) % 3][mi] = *(const bf16x8*)(wn_ + mi * 512);
      }
      if (ti == 0 && ch < 6) {  // breg issue AFTER first A-group: defers force-drain
#pragma unroll
        for (int i = 0; i < 3; ++i)
          if (Uok[i]) breg[i] = *(const uint4*)(Pptr[i] + (ch + 2) * 32);
      }
      __builtin_amdgcn_s_setprio(1);
#pragma unroll
      for (int ni = 0; ni < 4; ++ni) {
        bf16x8 b = brow[dyq + ni];
#pragma unroll
        for (int mi = 0; mi < 4; ++mi)
          acc[mi][ni] =
              __builtin_amdgcn_mfma_f32_16x16x32_bf16(areg[ti % 3][mi], b, acc[mi][ni], 0, 0, 0);
      }
      __builtin_amdgcn_s_setprio(0);
    }
    __syncthreads();  // one barrier per ch-step: stage(ch+1) visible, reads(ch) done
  }
  // epilogue: store raw bf16 NHWC + group stats
  if (t < 32) sred[t] = 0.f;
  __syncthreads();
  long pebase = (long)(pxb + (y0 + 1) * Wp + (x0 + col + 1)) * 256;
#pragma unroll
  for (int ni = 0; ni < 4; ++ni) {
    int row = wn * 4 + ni;
    if (y0 + row < H) {
#pragma unroll
      for (int mi = 0; mi < 4; ++mi) {
        f32x4 v = acc[mi][ni];
        int o = mo * 128 + wm * 64 + mi * 16 + quad * 4;
        uint2 pk;
        pk.x = cvtpk(v[0], v[1]);
        pk.y = cvtpk(v[2], v[3]);
        *(uint2*)(Yraw + pebase + (long)row * Wp * 256 + o) = pk;
      }
    }
  }
#pragma unroll
  for (int mi = 0; mi < 4; ++mi) {
    float s1 = 0.f, s2 = 0.f;
#pragma unroll
    for (int ni = 0; ni < 4; ++ni) {
      if (y0 + wn * 4 + ni < H) {
        f32x4 v = acc[mi][ni];
#pragma unroll
        for (int r2 = 0; r2 < 4; ++r2) { float f = v[r2]; s1 += f; s2 += f * f; }
      }
    }
#pragma unroll
    for (int m = 1; m < 16; m <<= 1) { s1 += __shfl_xor(s1, m); s2 += __shfl_xor(s2, m); }
    if (col == 0) {
      int g = (wm * 64 + mi * 16 + quad * 4) >> 3;
      atomicAdd(&sred[g * 2], s1);
      atomicAdd(&sred[g * 2 + 1], s2);
    }
  }
  __syncthreads();
  if (t < 32) atomicAdd(&stats[(lvl * 32 + mo * 16 + (t >> 1)) * 2 + (t & 1)], sred[t]);
}

// ---------------- fused head conv (tower-style): GN+ReLU on staging ----------------
// ht 0: cls(80)+ctr MT=96; ht 1: reg(4,exp) MT=16; ht 2: msk(36,exp) MT=48.
// 128-px tiles (428/head); 4 waves n-split: wave covers px-rows {2w,2w+1}; MI m-frags.
// A global->reg double-buffered; B plane-split Btile, double-buffered across
// ch-steps (one barrier per ch-step). Scheduling = r1 form (breg before ti-loop,
// no setprio): the r2 ti0-breg placement with 2-slot A force-drained HBM at ti=2.
__global__ __launch_bounds__(256, 3) void conv_head_fused(
    const u16* __restrict__ Xbase, long ACT, int htsel, const u16* __restrict__ Whead,
    float* __restrict__ out, const float* __restrict__ pcb, const float* __restrict__ ptb,
    const float* __restrict__ prb, const float* __restrict__ pmb,
    const float* __restrict__ sb, const float* __restrict__ sm,
    const float* __restrict__ scaleb, long sb_ts) {
  __shared__ __align__(16) u16 Btile[11520];
  __shared__ float shSB[512];
  int bx = blockIdx.x;
  int ht, r;
  if (htsel >= 0) { ht = htsel; r = bx; }
  else { ht = bx / 428; r = bx - ht * 428; }
  int MI, woff, mt32;
  const float* bias0;
  const float* scl;
  if (ht == 0)      { MI = 6; woff = 0;      mt32 = 3072; bias0 = pcb; scl = sb; }
  else if (ht == 1) { MI = 1; woff = 221184; mt32 = 512;  bias0 = prb; scl = sb; }
  else              { MI = 3; woff = 258048; mt32 = 1536; bias0 = pmb; scl = sm; }
  const u16* Xn = Xbase + ((htsel >= 0) ? 0 : (long)ht * ACT);
  int tloc, W, H, SX, pxb, lvl, npx;
  if (r < 320)      { lvl = 0; tloc = r;       W = 256; H = 160; SX = 4; pxb = 0;     npx = 40960; }
  else if (r < 400) { lvl = 1; tloc = r - 320; W = 128; H = 80;  SX = 3; pxb = 41796; npx = 10240; }
  else if (r < 420) { lvl = 2; tloc = r - 400; W = 64;  H = 40;  SX = 2; pxb = 52456; npx = 2560;  }
  else if (r < 426) { lvl = 3; tloc = r - 420; W = 32;  H = 20;  SX = 1; pxb = 55228; npx = 640;   }
  else              { lvl = 4; tloc = r - 426; W = 16;  H = 10;  SX = 0; pxb = 55976; npx = 160;   }
  int obm, obc = 0;
  if (ht == 0) {
    const int obms[5] = {0, 3276800, 4096000, 4300800, 4352000};
    const int obcs[5] = {4583040, 4624000, 4634240, 4636800, 4637440};
    obm = obms[lvl]; obc = obcs[lvl];
  } else if (ht == 1) {
    const int obms[5] = {4364800, 4528640, 4569600, 4579840, 4582400};
    obm = obms[lvl];
  } else {
    const int obms[5] = {4637600, 6112160, 6480800, 6572960, 6596000};
    obm = obms[lvl];
  }
  int Wp = W + 2;
  int ty = tloc >> SX, txi = tloc & ((1 << SX) - 1);
  int y0 = ty * 8, x0 = txi * 16;
  int t = threadIdx.x, lane = t & 63, wave = t >> 6;
  int quad = lane >> 4, col = lane & 15;
  const u16* Xb2 = Xn + (long)(pxb + y0 * Wp + x0) * 256;
  const u16* Wb = Whead + woff + (long)lane * 8;
  {
    float2 sv = *(const float2*)(scaleb + ht * sb_ts + (lvl * 256 + t) * 2);
    *(float2*)(&shSB[t * 2]) = sv;
  }
  const u16* Pptr[3];
  int Lo[3], Cb[3];
  bool Uok[3], Keep[3];
#pragma unroll
  for (int i = 0; i < 3; ++i) {
    int u = t + i * 256;
    Uok[i] = u < 720;
    int q = u & 3, p = u >> 2;
    int py = p / 18, px = p - py * 18;
    Pptr[i] = Xb2 + (long)(py * Wp + px) * 256 + q * 8;
    Lo[i] = q * 1440 + p * 8;
    Cb[i] = q * 8;
    int yg = y0 + py, xg = x0 + px;
    Keep[i] = (yg >= 1) && (yg <= H) && (xg >= 1) && (xg <= W);
  }
  uint4 breg[3];
#pragma unroll
  for (int i = 0; i < 3; ++i)
    if (Uok[i]) breg[i] = *(const uint4*)(Pptr[i]);
  bf16x8 areg[2][6];
#pragma unroll
  for (int mi = 0; mi < 6; ++mi)
    if (mi < MI) areg[0][mi] = *(const bf16x8*)(Wb + mi * 512);
  f32x4 acc[6][2] = {};
  int brbase = quad * 1440 + wave * 288 + col * 8;  // rows 2w.. , + r*144, + dx*8
  auto stage = [&](int bo, int cc) {
#pragma unroll
    for (int i = 0; i < 3; ++i) {
      if (Uok[i]) {
        uint4 v = breg[i];
        int cb2 = (Cb[i] + cc * 32) * 2;
        float4 s01 = *(const float4*)(&shSB[cb2]);
        float4 s23 = *(const float4*)(&shSB[cb2 + 4]);
        float4 s45 = *(const float4*)(&shSB[cb2 + 8]);
        float4 s67 = *(const float4*)(&shSB[cb2 + 12]);
        u32 wv[4] = {v.x, v.y, v.z, v.w};
        float sc[8] = {s01.x, s01.z, s23.x, s23.z, s45.x, s45.z, s67.x, s67.z};
        float bi[8] = {s01.y, s01.w, s23.y, s23.w, s45.y, s45.w, s67.y, s67.w};
        bool kp = Keep[i];
        u32 ow[4];
#pragma unroll
        for (int jj = 0; jj < 4; ++jj) {
          u32 lo32 = wv[jj] << 16, hi32 = wv[jj] & 0xffff0000u;
          float flo, fhi;
          __builtin_memcpy(&flo, &lo32, 4);
          __builtin_memcpy(&fhi, &hi32, 4);
          float f0 = fmaxf(flo * sc[2 * jj] + bi[2 * jj], 0.f);
          float f1 = fmaxf(fhi * sc[2 * jj + 1] + bi[2 * jj + 1], 0.f);
          ow[jj] = cvtpk(f0, f1);
        }
        v.x = kp ? ow[0] : 0u;
        v.y = kp ? ow[1] : 0u;
        v.z = kp ? ow[2] : 0u;
        v.w = kp ? ow[3] : 0u;
        *(uint4*)(Btile + bo + Lo[i]) = v;
      }
    }
  };
  __syncthreads();  // shSB visible
  stage(0, 0);
#pragma unroll
  for (int i = 0; i < 3; ++i)
    if (Uok[i]) breg[i] = *(const uint4*)(Pptr[i] + 32);
  __syncthreads();  // buf0 visible
  for (int ch = 0; ch < 8; ++ch) {
    int bb = (ch & 1) * 5760;
    if (ch < 7) stage(5760 - bb, ch + 1);
    if (ch < 6) {
#pragma unroll
      for (int i = 0; i < 3; ++i)
        if (Uok[i]) breg[i] = *(const uint4*)(Pptr[i] + (ch + 2) * 32);
    }
    bf16x8 brow[4];
#pragma unroll
    for (int ti = 0; ti < 9; ++ti) {
      int kt = ch * 9 + ti;
      int dxq = ti / 3, dyq = ti - dxq * 3;
      if (dyq == 0) {
#pragma unroll
        for (int rr = 0; rr < 4; ++rr)
          brow[rr] = *(const bf16x8*)(Btile + bb + brbase + rr * 144 + dxq * 8);
      }
      {  // prefetch A(kt+1); over-read at kt=71 stays inside d_ws, unused
        const u16* wn_ = Wb + (long)(kt + 1) * mt32;
#pragma unroll
        for (int mi = 0; mi < 6; ++mi)
          if (mi < MI) areg[(ti + 1) & 1][mi] = *(const bf16x8*)(wn_ + mi * 512);
      }
#pragma unroll
      for (int ni = 0; ni < 2; ++ni) {
        bf16x8 b = brow[dyq + ni];
#pragma unroll
        for (int mi = 0; mi < 6; ++mi)
          if (mi < MI)
            acc[mi][ni] =
                __builtin_amdgcn_mfma_f32_16x16x32_bf16(areg[ti & 1][mi], b, acc[mi][ni], 0, 0, 0);
      }
    }
#pragma unroll
    for (int mi = 0; mi < 6; ++mi)
      if (mi < MI) areg[0][mi] = areg[1][mi];
    __syncthreads();
  }
  // epilogue: bias (+scale/exp) -> fp32 NCHW
  float scv = scl[lvl];
  int x = x0 + col;
#pragma unroll
  for (int ni = 0; ni < 2; ++ni) {
    int y = y0 + 2 * wave + ni;
    if (y < H) {
#pragma unroll
      for (int mi = 0; mi < 6; ++mi) {
        if (mi < MI) {
#pragma unroll
          for (int r2 = 0; r2 < 4; ++r2) {
            int o = mi * 16 + quad * 4 + r2;
            float v = acc[mi][ni][r2];
            if (ht == 0) {
              if (o < 80) out[obm + o * npx + y * W + x] = v + bias0[o];
              else if (o == 80) out[obc + y * W + x] = v + ptb[0];
            } else if (ht == 1) {
              if (o < 4) out[obm + o * npx + y * W + x] = expf((v + bias0[o]) * scv);
            } else {
              if (o < 36) out[obm + o * npx + y * W + x] = expf((v + bias0[o]) * scv);
            }
          }
        }
      }
    }
  }
}

extern "C" void kernel_launch(void* const* d_in, const int* in_sizes, int n_in,
                              void* d_out, int out_size, void* d_ws, size_t ws_size,
                              hipStream_t stream) {
  const float* feat0 = (const float*)d_in[0];
  const float* feat1 = (const float*)d_in[1];
  const float* feat2 = (const float*)d_in[2];
  const float* feat3 = (const float*)d_in[3];
  const float* feat4 = (const float*)d_in[4];
  const float* cw = (const float*)d_in[5];
  const float* rw = (const float*)d_in[8];
  const float* mw = (const float*)d_in[11];
  const float* gmas[3] = {(const float*)d_in[6], (const float*)d_in[9], (const float*)d_in[12]};
  const float* btas[3] = {(const float*)d_in[7], (const float*)d_in[10], (const float*)d_in[13]};
  const float* pcw = (const float*)d_in[14];
  const float* pcb = (const float*)d_in[15];
  const float* prw = (const float*)d_in[16];
  const float* prb = (const float*)d_in[17];
  const float* pmw = (const float*)d_in[18];
  const float* pmb = (const float*)d_in[19];
  const float* ptw = (const float*)d_in[20];
  const float* ptb = (const float*)d_in[21];
  const float* sb = (const float*)d_in[22];
  const float* sm = (const float*)d_in[23];
  float* out = (float*)d_out;

  const long ACT = 14385152;         // u16 elems per tower activation buffer
  const long ACTB = 28770304;        // bytes
  const long WTS = 14893056;         // bytes of converted weights
  char* base = (char*)d_ws;
  u16* wts = (u16*)base;

  // fused layout: wts | X3 (3) | Y3 (3) | stats (3840 B) | scaleb (30720 B) | 64 KB slack
  size_t need_fused = WTS + 6 * (size_t)ACTB + 3840 + 30720 + 65536;

  convert_weights<<<29088, 256, 0, stream>>>(cw, rw, mw, pcw, prw, pmw, ptw, wts);

  if (ws_size >= need_fused) {
    u16* X = (u16*)(base + WTS);
    u16* Y = (u16*)(base + WTS + 3 * ACTB);
    float* stats = (float*)(base + WTS + 6 * ACTB);
    float* scaleb = (float*)(base + WTS + 6 * ACTB + 3840);
    halo_zero<<<612, 256, 0, stream>>>(X, Y, ACT, 3);
    feat_to_nhwc<<<3412, 256, 0, stream>>>(feat0, feat1, feat2, feat3, feat4, X, ACT, 1);
    for (int s = 0; s < 4; ++s) {
      u16* in = (s & 1) ? Y : X;
      u16* ot = (s & 1) ? X : Y;
      long ints = (s == 0) ? 0 : ACT;  // s=0: all towers share the single staged input
      hipMemsetAsync(stats, 0, 3840, stream);
      conv_tower<<<2568, 256, 0, stream>>>(in, ints, wts + s * 589824, 4 * 589824, ot, ACT,
                                           stats, 320, scaleb, 2560, s > 0);
      finalize_stats<<<15, 256, 0, stream>>>(stats, 320,
                                             gmas[0] + s * 256, gmas[1] + s * 256, gmas[2] + s * 256,
                                             btas[0] + s * 256, btas[1] + s * 256, btas[2] + s * 256,
                                             scaleb, 2560, 3);
    }
    // s=3 raw output is in X; heads apply GN+ReLU (s=3 scaleb) during staging
    conv_head_fused<<<1284, 256, 0, stream>>>(X, ACT, -1, wts + 7077888, out,
                                              pcb, ptb, prb, pmb, sb, sm, scaleb, 2560);
  } else {
    // -------- fallback: sequential towers --------
    u16* bufA = (u16*)(base + WTS);
    u16* bufB = (u16*)(base + WTS + ACTB);
    float* stats = (float*)(base + WTS + 2 * ACTB);
    float* scaleb = (float*)(base + WTS + 2 * ACTB + 1280);
    halo_zero<<<204, 256, 0, stream>>>(bufA, bufB, 0, 1);
    for (int tw = 0; tw < 3; ++tw) {
      feat_to_nhwc<<<3412, 256, 0, stream>>>(feat0, feat1, feat2, feat3, feat4, bufA, 0, 1);
      for (int s = 0; s < 4; ++s) {
        u16* in = (s & 1) ? bufB : bufA;
        u16* ot = (s & 1) ? bufA : bufB;
        hipMemsetAsync(stats, 0, 1280, stream);
        conv_tower<<<856, 256, 0, stream>>>(in, 0, wts + (tw * 4 + s) * 589824, 0, ot, 0,
                                            stats, 0, scaleb, 0, s > 0);
        finalize_stats<<<5, 256, 0, stream>>>(stats, 0,
                                              gmas[tw] + s * 256, gmas[tw] + s * 256, gmas[tw] + s * 256,
                                              btas[tw] + s * 256, btas[tw] + s * 256, btas[tw] + s * 256,
                                              scaleb, 0, 1);
      }
      // s=3 raw output in bufA; head applies GN via scaleb (sb_ts=0)
      conv_head_fused<<<428, 256, 0, stream>>>(bufA, 0, tw, wts + 7077888, out,
                                               pcb, ptb, prb, pmb, sb, sm, scaleb, 0);
    }
  }
}

// Round 9
// 957.581 us; speedup vs baseline: 1.0324x; 1.0324x over previous
//
#include <hip/hip_runtime.h>

typedef unsigned short u16;
typedef unsigned int u32;
typedef short bf16x8 __attribute__((ext_vector_type(8)));
typedef float f32x4 __attribute__((ext_vector_type(4)));

__device__ __forceinline__ float bf2f(u16 u) {
  u32 x = ((u32)u) << 16;
  float f;
  __builtin_memcpy(&f, &x, 4);
  return f;
}
__device__ __forceinline__ u16 f2bf(float f) {
  u32 x;
  __builtin_memcpy(&x, &f, 4);
  u32 r = x + 0x7FFFu + ((x >> 16) & 1u);
  return (u16)(r >> 16);
}
// pack two fp32 -> bf16x2 (round-to-nearest-half-up): 2 adds + v_perm
__device__ __forceinline__ u32 pack2(float f0, float f1) {
  u32 a, b;
  __builtin_memcpy(&a, &f0, 4);
  __builtin_memcpy(&b, &f1, 4);
  a += 0x8000u;
  b += 0x8000u;
  return __builtin_amdgcn_perm(b, a, 0x07060302);
}
// pack two fp32 -> bf16x2 in ONE VALU op (RTNE): v_cvt_pk_bf16_f32 (gfx950)
__device__ __forceinline__ u32 cvtpk(float f0, float f1) {
  u32 r;
  asm("v_cvt_pk_bf16_f32 %0, %1, %2" : "=v"(r) : "v"(f0), "v"(f1));
  return r;
}
// LDS-only barrier: drain lgkm (ds ops) but keep global loads (vmcnt) IN FLIGHT.
// __syncthreads() would emit s_waitcnt vmcnt(0) and force-drain A/breg prefetch.
__device__ __forceinline__ void lds_barrier() {
  asm volatile("s_waitcnt lgkmcnt(0)" ::: "memory");
  __builtin_amdgcn_s_barrier();
}

// ---------------- geometry ----------------
// levels: W {256,128,64,32,16} H {160,80,40,20,10}; padded (W+2)x(H+2) NHWC bf16
// padded pixel bases {0, 41796, 52456, 55228, 55976}; total 56192 px
// per-tower activation stride = 56192*256 = 14,385,152 u16 elements

// ---------------- weight conversion ----------------
// tower layout per conv (A-fragment order): [mo(2)][kt(72)][wm(2)][mi(4)][lane(64)][j(8)]
//   kt = ch*9 + ti, ti = dx*3+dy (dx-major for B row caching)
// head layout: [kt(72)][mi(MI)][lane(64)][j(8)] per head; cls MT=96 (80+ctr+pad),
//   reg MT=16 (4+pad), msk MT=48 (36+pad); offsets 0 / 221184 / 258048.
__global__ void convert_weights(const float* __restrict__ cw, const float* __restrict__ rw,
                                const float* __restrict__ mw, const float* __restrict__ pc,
                                const float* __restrict__ pr, const float* __restrict__ pm,
                                const float* __restrict__ pt, u16* __restrict__ dst) {
  int e = blockIdx.x * 256 + threadIdx.x;
  if (e >= 7446528) return;
  float v = 0.f;
  if (e < 7077888) {
    int conv = e / 589824, r = e % 589824;
    int mo = r / 294912;
    int r2 = r - mo * 294912;
    int kt = r2 >> 12;
    int r3 = r2 & 4095;
    int wm = r3 >> 11;
    int mi = (r3 >> 9) & 3;
    int l = (r3 >> 3) & 63;
    int j = r3 & 7;
    int ch = kt / 9, ti = kt - ch * 9;
    int dxs = ti / 3, dys = ti - dxs * 3;
    int tap = dys * 3 + dxs;
    int o = mo * 128 + wm * 64 + mi * 16 + (l & 15);
    int c = ch * 32 + (l >> 4) * 8 + j;
    const float* s = (conv < 4) ? cw : (conv < 8) ? rw : mw;
    int si = conv & 3;
    v = s[((si * 256 + o) * 256 + c) * 9 + tap];
  } else {
    int e2 = e - 7077888;
    int kt, r2, mi, mtsel;
    const float* src = nullptr;
    int olim = 0;
    bool ctr = false;
    if (e2 < 221184) {        // cls MT=96
      kt = e2 / 3072; r2 = e2 % 3072; mi = r2 / 512; r2 %= 512;
      src = pc; olim = 80; ctr = true;
    } else if (e2 < 258048) { // reg MT=16
      int e3 = e2 - 221184;
      kt = e3 / 512; r2 = e3 % 512; mi = 0;
      src = pr; olim = 4;
    } else {                  // msk MT=48
      int e3 = e2 - 258048;
      kt = e3 / 1536; r2 = e3 % 1536; mi = r2 / 512; r2 %= 512;
      src = pm; olim = 36;
    }
    int l = r2 >> 3, j = r2 & 7;
    int ch = kt / 9, ti = kt - ch * 9;
    int dxs = ti / 3, dys = ti - dxs * 3;
    int tap = dys * 3 + dxs;
    int o = mi * 16 + (l & 15);
    int c = ch * 32 + (l >> 4) * 8 + j;
    if (o < olim) v = src[(o * 256 + c) * 9 + tap];
    else if (ctr && o == 80) v = pt[c * 9 + tap];
    (void)mtsel;
  }
  dst[e] = f2bf(v);
}

// ---------------- halo zero: clear 1-px border of padded buffers ----------------
__global__ void halo_zero(u16* __restrict__ X, u16* __restrict__ Y, long ACT, int ntw) {
  int i = blockIdx.x * 256 + threadIdx.x;
  int rep = i / 26112;         // 1632*16
  int j = i - rep * 26112;
  if (rep >= 2 * ntw) return;
  int hp = j >> 4, sub = j & 15;
  int Wp, Hp, pxb, h;
  if (hp < 836)       { Wp = 258; Hp = 162; pxb = 0;     h = hp; }
  else if (hp < 1256) { Wp = 130; Hp = 82;  pxb = 41796; h = hp - 836; }
  else if (hp < 1468) { Wp = 66;  Hp = 42;  pxb = 52456; h = hp - 1256; }
  else if (hp < 1576) { Wp = 34;  Hp = 22;  pxb = 55228; h = hp - 1468; }
  else                { Wp = 18;  Hp = 12;  pxb = 55976; h = hp - 1576; }
  int y, x;
  if (h < Wp)          { y = 0;      x = h; }
  else if (h < 2 * Wp) { y = Hp - 1; x = h - Wp; }
  else {
    int rr = h - 2 * Wp;
    y = 1 + (rr >> 1);
    x = (rr & 1) ? (Wp - 1) : 0;
  }
  u16* buf = (rep < ntw) ? (X + rep * ACT) : (Y + (rep - ntw) * ACT);
  long adr = (long)(pxb + y * Wp + x) * 256 + sub * 16;
  uint4 z = {0, 0, 0, 0};
  *(uint4*)(buf + adr) = z;
  *(uint4*)(buf + adr + 8) = z;
}

// ---------------- feat NCHW fp32 -> padded NHWC bf16 ----------------
__global__ void feat_to_nhwc(const float* __restrict__ f0, const float* __restrict__ f1,
                             const float* __restrict__ f2, const float* __restrict__ f3,
                             const float* __restrict__ f4, u16* __restrict__ dst,
                             long tstride, int nrep) {
  __shared__ float lds[64 * 65];
  int bx = blockIdx.x;
  int tile = bx >> 2, c0 = (bx & 3) * 64;
  int tl, sh, pxb, npx;
  const float* src;
  if (tile < 640)      { tl = tile;       sh = 8; pxb = 0;     npx = 40960; src = f0; }
  else if (tile < 800) { tl = tile - 640; sh = 7; pxb = 41796; npx = 10240; src = f1; }
  else if (tile < 840) { tl = tile - 800; sh = 6; pxb = 52456; npx = 2560;  src = f2; }
  else if (tile < 850) { tl = tile - 840; sh = 5; pxb = 55228; npx = 640;   src = f3; }
  else                 { tl = tile - 850; sh = 4; pxb = 55976; npx = 160;   src = f4; }
  int W = 1 << sh, Wp = W + 2;
  int px0 = tl * 64;
  int t = threadIdx.x;
  {
    int cc = (t >> 6) * 16, px = t & 63;
    bool ok = (px0 + px) < npx;
#pragma unroll
    for (int j = 0; j < 16; ++j) {
      float v = ok ? src[(c0 + cc + j) * npx + px0 + px] : 0.f;
      lds[(cc + j) * 65 + px] = v;
    }
  }
  __syncthreads();
  {
    int px = t >> 2, cL = (t & 3) * 16;
    int pxi = px0 + px;
    if (pxi < npx) {
      int y = pxi >> sh, x = pxi & (W - 1);
      u32 w[8];
#pragma unroll
      for (int j = 0; j < 8; ++j)
        w[j] = pack2(lds[(cL + 2 * j) * 65 + px], lds[(cL + 2 * j + 1) * 65 + px]);
      long adr = (long)(pxb + (y + 1) * Wp + (x + 1)) * 256 + c0 + cL;
      uint4 v0 = {w[0], w[1], w[2], w[3]}, v1 = {w[4], w[5], w[6], w[7]};
      for (int r = 0; r < nrep; ++r) {
        *(uint4*)(dst + r * tstride + adr) = v0;
        *(uint4*)(dst + r * tstride + adr + 8) = v1;
      }
    }
  }
}

// ---------------- finalize GN stats -> per-channel (scale, bias) ----------------
__global__ void finalize_stats(const float* __restrict__ stats, int st_ts,
                               const float* __restrict__ g0, const float* __restrict__ g1,
                               const float* __restrict__ g2, const float* __restrict__ b0,
                               const float* __restrict__ b1, const float* __restrict__ b2,
                               float* __restrict__ scaleb, int sb_ts, int ntw) {
  int i = blockIdx.x * 256 + threadIdx.x;
  if (i >= ntw * 1280) return;
  int tw = i / 1280, r = i - tw * 1280, lvl = r >> 8, c = r & 255, g = c >> 3;
  float cnt = (lvl == 0) ? 327680.f : (lvl == 1) ? 81920.f
              : (lvl == 2) ? 20480.f : (lvl == 3) ? 5120.f : 1280.f;
  float s1 = stats[tw * st_ts + (lvl * 32 + g) * 2];
  float s2 = stats[tw * st_ts + (lvl * 32 + g) * 2 + 1];
  float mean = s1 / cnt;
  float var = s2 / cnt - mean * mean;
  float inv = rsqrtf(fmaxf(var, 0.f) + 1e-5f);
  const float* ga = (tw == 0) ? g0 : (tw == 1) ? g1 : g2;
  const float* be = (tw == 0) ? b0 : (tw == 1) ? b1 : b2;
  float sc = inv * ga[c];
  scaleb[(long)tw * sb_ts + (lvl * 256 + c) * 2] = sc;
  scaleb[(long)tw * sb_ts + (lvl * 256 + c) * 2 + 1] = be[c] - mean * sc;
}

// ---------------- tower conv: 256->256 3x3, bf16 MFMA implicit GEMM ----------------
// 128 o x 128 px block, 4 waves, 4x4 frags. A global->registers (fragment order),
// DEPTH-2 prefetch via 3-slot rotation (kt%3 == ti%3, all indices compile-time).
// B: plane-split LDS tile, double-buffered across ch-steps, ONE LDS-only barrier
// per ch-step (lgkmcnt(0)+s_barrier — vmcnt prefetches stay in flight; a full
// __syncthreads here would vmcnt(0)-drain the A/breg prefetch every step).
// breg issued inside ti=0 (after first A-group issue). setprio(1) around MFMA.
__global__ __launch_bounds__(256, 3) void conv_tower(
    const u16* __restrict__ Xn, long in_ts, const u16* __restrict__ Wt, long wt_ts,
    u16* __restrict__ Yraw, long out_ts, float* __restrict__ stats, int st_ts,
    const float* __restrict__ scaleb, int sb_ts, int do_gn) {
  __shared__ __align__(16) u16 Btile[11520];  // 2 x (4 planes x 180 px x 8 ch)
  __shared__ float shSB[512];                 // (scale,bias) per channel
  __shared__ float sred[32];
  int bx = blockIdx.x;
  int tw = bx / 856, r856 = bx - tw * 856;
  Xn += tw * in_ts; Wt += tw * wt_ts; Yraw += tw * out_ts; stats += tw * st_ts;
  int tile = r856 >> 1, mo = r856 & 1;
  int tloc, W, H, SX, pxb, lvl;
  if (tile < 320)      { lvl = 0; tloc = tile;       W = 256; H = 160; SX = 4; pxb = 0; }
  else if (tile < 400) { lvl = 1; tloc = tile - 320; W = 128; H = 80;  SX = 3; pxb = 41796; }
  else if (tile < 420) { lvl = 2; tloc = tile - 400; W = 64;  H = 40;  SX = 2; pxb = 52456; }
  else if (tile < 426) { lvl = 3; tloc = tile - 420; W = 32;  H = 20;  SX = 1; pxb = 55228; }
  else                 { lvl = 4; tloc = tile - 426; W = 16;  H = 10;  SX = 0; pxb = 55976; }
  int Wp = W + 2;
  int ty = tloc >> SX, txi = tloc & ((1 << SX) - 1);
  int y0 = ty * 8, x0 = txi * 16;
  int t = threadIdx.x, lane = t & 63, wave = t >> 6;
  int wm = wave >> 1, wn = wave & 1;
  int quad = lane >> 4, col = lane & 15;
  const u16* Xbase = Xn + (long)(pxb + y0 * Wp + x0) * 256;
  const u16* Wb = Wt + (long)mo * 294912 + wm * 2048 + (long)lane * 8;
  int bcol = quad * 1440 + wn * 576 + col * 8;
  if (do_gn) {
    float2 sv = *(const float2*)(scaleb + (long)tw * sb_ts + (lvl * 256 + t) * 2);
    *(float2*)(&shSB[t * 2]) = sv;
  }
  const u16* Pptr[3];
  int Lo[3], Cb[3];
  bool Uok[3], Keep[3];
#pragma unroll
  for (int i = 0; i < 3; ++i) {
    int u = t + i * 256;
    Uok[i] = u < 720;
    int q = u & 3, p = u >> 2;
    int py = p / 18, px = p - py * 18;
    Pptr[i] = Xbase + (long)(py * Wp + px) * 256 + q * 8;
    Lo[i] = q * 1440 + p * 8;
    Cb[i] = q * 8;
    int yg = y0 + py, xg = x0 + px;
    Keep[i] = (yg >= 1) && (yg <= H) && (xg >= 1) && (xg <= W);
  }
  uint4 breg[3];
#pragma unroll
  for (int i = 0; i < 3; ++i)
    if (Uok[i]) breg[i] = *(const uint4*)(Pptr[i]);
  // 3-slot A rotation: slot[kt%3]; since kt = ch*9+ti and 9%3==0, slot == ti%3.
  bf16x8 areg[3][4];
#pragma unroll
  for (int mi = 0; mi < 4; ++mi) areg[0][mi] = *(const bf16x8*)(Wb + mi * 512);
#pragma unroll
  for (int mi = 0; mi < 4; ++mi) areg[1][mi] = *(const bf16x8*)(Wb + 4096 + mi * 512);
  f32x4 acc[4][4] = {};
  // stage breg (channel group cc) into Btile[bo..] with fused GN+ReLU
  auto stage = [&](int bo, int cc) {
#pragma unroll
    for (int i = 0; i < 3; ++i) {
      if (Uok[i]) {
        uint4 v = breg[i];
        if (do_gn) {
          int cb2 = (Cb[i] + cc * 32) * 2;
          float4 s01 = *(const float4*)(&shSB[cb2]);
          float4 s23 = *(const float4*)(&shSB[cb2 + 4]);
          float4 s45 = *(const float4*)(&shSB[cb2 + 8]);
          float4 s67 = *(const float4*)(&shSB[cb2 + 12]);
          u32 wv[4] = {v.x, v.y, v.z, v.w};
          float sc[8] = {s01.x, s01.z, s23.x, s23.z, s45.x, s45.z, s67.x, s67.z};
          float bi[8] = {s01.y, s01.w, s23.y, s23.w, s45.y, s45.w, s67.y, s67.w};
          bool kp = Keep[i];
          u32 ow[4];
#pragma unroll
          for (int jj = 0; jj < 4; ++jj) {
            u32 lo32 = wv[jj] << 16, hi32 = wv[jj] & 0xffff0000u;
            float flo, fhi;
            __builtin_memcpy(&flo, &lo32, 4);
            __builtin_memcpy(&fhi, &hi32, 4);
            float f0 = fmaxf(flo * sc[2 * jj] + bi[2 * jj], 0.f);
            float f1 = fmaxf(fhi * sc[2 * jj + 1] + bi[2 * jj + 1], 0.f);
            ow[jj] = cvtpk(f0, f1);
          }
          v.x = kp ? ow[0] : 0u;
          v.y = kp ? ow[1] : 0u;
          v.z = kp ? ow[2] : 0u;
          v.w = kp ? ow[3] : 0u;
        }
        *(uint4*)(Btile + bo + Lo[i]) = v;
      }
    }
  };
  __syncthreads();  // shSB visible before prologue staging
  stage(0, 0);      // prologue: stage ch0 -> buf0
#pragma unroll
  for (int i = 0; i < 3; ++i)
    if (Uok[i]) breg[i] = *(const uint4*)(Pptr[i] + 32);  // prefetch ch1
  __syncthreads();  // buf0 visible
  for (int ch = 0; ch < 8; ++ch) {
    int bb = (ch & 1) * 5760;
    if (ch < 7) stage(5760 - bb, ch + 1);  // overlaps with MFMA below (other buffer)
    bf16x8 brow[6];
#pragma unroll
    for (int ti = 0; ti < 9; ++ti) {
      int kt = ch * 9 + ti;
      int dxq = ti / 3, dyq = ti - dxq * 3;
      if (dyq == 0) {
#pragma unroll
        for (int r = 0; r < 6; ++r)
          brow[r] = *(const bf16x8*)(Btile + bb + bcol + r * 144 + dxq * 8);
      }
      {  // prefetch A(kt+2) into slot (ti+2)%3; kt=70/71 over-read stays inside wts
        const u16* wn_ = Wb + (long)(kt + 2) * 4096;
#pragma unroll
        for (int mi = 0; mi < 4; ++mi)
          areg[(ti + 2) % 3][mi] = *(const bf16x8*)(wn_ + mi * 512);
      }
      if (ti == 0 && ch < 6) {  // breg issue AFTER first A-group: defers force-drain
#pragma unroll
        for (int i = 0; i < 3; ++i)
          if (Uok[i]) breg[i] = *(const uint4*)(Pptr[i] + (ch + 2) * 32);
      }
      __builtin_amdgcn_s_setprio(1);
#pragma unroll
      for (int ni = 0; ni < 4; ++ni) {
        bf16x8 b = brow[dyq + ni];
#pragma unroll
        for (int mi = 0; mi < 4; ++mi)
          acc[mi][ni] =
              __builtin_amdgcn_mfma_f32_16x16x32_bf16(areg[ti % 3][mi], b, acc[mi][ni], 0, 0, 0);
      }
      __builtin_amdgcn_s_setprio(0);
    }
    lds_barrier();  // LDS-only: stage(ch+1) visible, reads(ch) done; vmcnt kept
  }
  // epilogue: store raw bf16 NHWC + group stats
  if (t < 32) sred[t] = 0.f;
  __syncthreads();
  long pebase = (long)(pxb + (y0 + 1) * Wp + (x0 + col + 1)) * 256;
#pragma unroll
  for (int ni = 0; ni < 4; ++ni) {
    int row = wn * 4 + ni;
    if (y0 + row < H) {
#pragma unroll
      for (int mi = 0; mi < 4; ++mi) {
        f32x4 v = acc[mi][ni];
        int o = mo * 128 + wm * 64 + mi * 16 + quad * 4;
        uint2 pk;
        pk.x = cvtpk(v[0], v[1]);
        pk.y = cvtpk(v[2], v[3]);
        *(uint2*)(Yraw + pebase + (long)row * Wp * 256 + o) = pk;
      }
    }
  }
#pragma unroll
  for (int mi = 0; mi < 4; ++mi) {
    float s1 = 0.f, s2 = 0.f;
#pragma unroll
    for (int ni = 0; ni < 4; ++ni) {
      if (y0 + wn * 4 + ni < H) {
        f32x4 v = acc[mi][ni];
#pragma unroll
        for (int r2 = 0; r2 < 4; ++r2) { float f = v[r2]; s1 += f; s2 += f * f; }
      }
    }
#pragma unroll
    for (int m = 1; m < 16; m <<= 1) { s1 += __shfl_xor(s1, m); s2 += __shfl_xor(s2, m); }
    if (col == 0) {
      int g = (wm * 64 + mi * 16 + quad * 4) >> 3;
      atomicAdd(&sred[g * 2], s1);
      atomicAdd(&sred[g * 2 + 1], s2);
    }
  }
  __syncthreads();
  if (t < 32) atomicAdd(&stats[(lvl * 32 + mo * 16 + (t >> 1)) * 2 + (t & 1)], sred[t]);
}

// ---------------- fused head conv (tower-style): GN+ReLU on staging ----------------
// ht 0: cls(80)+ctr MT=96; ht 1: reg(4,exp) MT=16; ht 2: msk(36,exp) MT=48.
// 128-px tiles (428/head); 4 waves n-split: wave covers px-rows {2w,2w+1}; MI m-frags.
// A global->reg double-buffered; B plane-split Btile, double-buffered across
// ch-steps with ONE LDS-only barrier per ch-step (vmcnt kept in flight).
__global__ __launch_bounds__(256, 3) void conv_head_fused(
    const u16* __restrict__ Xbase, long ACT, int htsel, const u16* __restrict__ Whead,
    float* __restrict__ out, const float* __restrict__ pcb, const float* __restrict__ ptb,
    const float* __restrict__ prb, const float* __restrict__ pmb,
    const float* __restrict__ sb, const float* __restrict__ sm,
    const float* __restrict__ scaleb, long sb_ts) {
  __shared__ __align__(16) u16 Btile[11520];
  __shared__ float shSB[512];
  int bx = blockIdx.x;
  int ht, r;
  if (htsel >= 0) { ht = htsel; r = bx; }
  else { ht = bx / 428; r = bx - ht * 428; }
  int MI, woff, mt32;
  const float* bias0;
  const float* scl;
  if (ht == 0)      { MI = 6; woff = 0;      mt32 = 3072; bias0 = pcb; scl = sb; }
  else if (ht == 1) { MI = 1; woff = 221184; mt32 = 512;  bias0 = prb; scl = sb; }
  else              { MI = 3; woff = 258048; mt32 = 1536; bias0 = pmb; scl = sm; }
  const u16* Xn = Xbase + ((htsel >= 0) ? 0 : (long)ht * ACT);
  int tloc, W, H, SX, pxb, lvl, npx;
  if (r < 320)      { lvl = 0; tloc = r;       W = 256; H = 160; SX = 4; pxb = 0;     npx = 40960; }
  else if (r < 400) { lvl = 1; tloc = r - 320; W = 128; H = 80;  SX = 3; pxb = 41796; npx = 10240; }
  else if (r < 420) { lvl = 2; tloc = r - 400; W = 64;  H = 40;  SX = 2; pxb = 52456; npx = 2560;  }
  else if (r < 426) { lvl = 3; tloc = r - 420; W = 32;  H = 20;  SX = 1; pxb = 55228; npx = 640;   }
  else              { lvl = 4; tloc = r - 426; W = 16;  H = 10;  SX = 0; pxb = 55976; npx = 160;   }
  int obm, obc = 0;
  if (ht == 0) {
    const int obms[5] = {0, 3276800, 4096000, 4300800, 4352000};
    const int obcs[5] = {4583040, 4624000, 4634240, 4636800, 4637440};
    obm = obms[lvl]; obc = obcs[lvl];
  } else if (ht == 1) {
    const int obms[5] = {4364800, 4528640, 4569600, 4579840, 4582400};
    obm = obms[lvl];
  } else {
    const int obms[5] = {4637600, 6112160, 6480800, 6572960, 6596000};
    obm = obms[lvl];
  }
  int Wp = W + 2;
  int ty = tloc >> SX, txi = tloc & ((1 << SX) - 1);
  int y0 = ty * 8, x0 = txi * 16;
  int t = threadIdx.x, lane = t & 63, wave = t >> 6;
  int quad = lane >> 4, col = lane & 15;
  const u16* Xb2 = Xn + (long)(pxb + y0 * Wp + x0) * 256;
  const u16* Wb = Whead + woff + (long)lane * 8;
  {
    float2 sv = *(const float2*)(scaleb + ht * sb_ts + (lvl * 256 + t) * 2);
    *(float2*)(&shSB[t * 2]) = sv;
  }
  const u16* Pptr[3];
  int Lo[3], Cb[3];
  bool Uok[3], Keep[3];
#pragma unroll
  for (int i = 0; i < 3; ++i) {
    int u = t + i * 256;
    Uok[i] = u < 720;
    int q = u & 3, p = u >> 2;
    int py = p / 18, px = p - py * 18;
    Pptr[i] = Xb2 + (long)(py * Wp + px) * 256 + q * 8;
    Lo[i] = q * 1440 + p * 8;
    Cb[i] = q * 8;
    int yg = y0 + py, xg = x0 + px;
    Keep[i] = (yg >= 1) && (yg <= H) && (xg >= 1) && (xg <= W);
  }
  uint4 breg[3];
#pragma unroll
  for (int i = 0; i < 3; ++i)
    if (Uok[i]) breg[i] = *(const uint4*)(Pptr[i]);
  bf16x8 areg[2][6];
#pragma unroll
  for (int mi = 0; mi < 6; ++mi)
    if (mi < MI) areg[0][mi] = *(const bf16x8*)(Wb + mi * 512);
  f32x4 acc[6][2] = {};
  int brbase = quad * 1440 + wave * 288 + col * 8;  // rows 2w.. , + r*144, + dx*8
  auto stage = [&](int bo, int cc) {
#pragma unroll
    for (int i = 0; i < 3; ++i) {
      if (Uok[i]) {
        uint4 v = breg[i];
        int cb2 = (Cb[i] + cc * 32) * 2;
        float4 s01 = *(const float4*)(&shSB[cb2]);
        float4 s23 = *(const float4*)(&shSB[cb2 + 4]);
        float4 s45 = *(const float4*)(&shSB[cb2 + 8]);
        float4 s67 = *(const float4*)(&shSB[cb2 + 12]);
        u32 wv[4] = {v.x, v.y, v.z, v.w};
        float sc[8] = {s01.x, s01.z, s23.x, s23.z, s45.x, s45.z, s67.x, s67.z};
        float bi[8] = {s01.y, s01.w, s23.y, s23.w, s45.y, s45.w, s67.y, s67.w};
        bool kp = Keep[i];
        u32 ow[4];
#pragma unroll
        for (int jj = 0; jj < 4; ++jj) {
          u32 lo32 = wv[jj] << 16, hi32 = wv[jj] & 0xffff0000u;
          float flo, fhi;
          __builtin_memcpy(&flo, &lo32, 4);
          __builtin_memcpy(&fhi, &hi32, 4);
          float f0 = fmaxf(flo * sc[2 * jj] + bi[2 * jj], 0.f);
          float f1 = fmaxf(fhi * sc[2 * jj + 1] + bi[2 * jj + 1], 0.f);
          ow[jj] = cvtpk(f0, f1);
        }
        v.x = kp ? ow[0] : 0u;
        v.y = kp ? ow[1] : 0u;
        v.z = kp ? ow[2] : 0u;
        v.w = kp ? ow[3] : 0u;
        *(uint4*)(Btile + bo + Lo[i]) = v;
      }
    }
  };
  __syncthreads();  // shSB visible
  stage(0, 0);
#pragma unroll
  for (int i = 0; i < 3; ++i)
    if (Uok[i]) breg[i] = *(const uint4*)(Pptr[i] + 32);
  __syncthreads();  // buf0 visible
  for (int ch = 0; ch < 8; ++ch) {
    int bb = (ch & 1) * 5760;
    if (ch < 7) stage(5760 - bb, ch + 1);
    if (ch < 6) {
#pragma unroll
      for (int i = 0; i < 3; ++i)
        if (Uok[i]) breg[i] = *(const uint4*)(Pptr[i] + (ch + 2) * 32);
    }
    bf16x8 brow[4];
#pragma unroll
    for (int ti = 0; ti < 9; ++ti) {
      int kt = ch * 9 + ti;
      int dxq = ti / 3, dyq = ti - dxq * 3;
      if (dyq == 0) {
#pragma unroll
        for (int rr = 0; rr < 4; ++rr)
          brow[rr] = *(const bf16x8*)(Btile + bb + brbase + rr * 144 + dxq * 8);
      }
      {  // prefetch A(kt+1); over-read at kt=71 stays inside d_ws, unused
        const u16* wn_ = Wb + (long)(kt + 1) * mt32;
#pragma unroll
        for (int mi = 0; mi < 6; ++mi)
          if (mi < MI) areg[(ti + 1) & 1][mi] = *(const bf16x8*)(wn_ + mi * 512);
      }
#pragma unroll
      for (int ni = 0; ni < 2; ++ni) {
        bf16x8 b = brow[dyq + ni];
#pragma unroll
        for (int mi = 0; mi < 6; ++mi)
          if (mi < MI)
            acc[mi][ni] =
                __builtin_amdgcn_mfma_f32_16x16x32_bf16(areg[ti & 1][mi], b, acc[mi][ni], 0, 0, 0);
      }
    }
#pragma unroll
    for (int mi = 0; mi < 6; ++mi)
      if (mi < MI) areg[0][mi] = areg[1][mi];
    lds_barrier();  // LDS-only barrier: vmcnt prefetches stay in flight
  }
  // epilogue: bias (+scale/exp) -> fp32 NCHW
  float scv = scl[lvl];
  int x = x0 + col;
#pragma unroll
  for (int ni = 0; ni < 2; ++ni) {
    int y = y0 + 2 * wave + ni;
    if (y < H) {
#pragma unroll
      for (int mi = 0; mi < 6; ++mi) {
        if (mi < MI) {
#pragma unroll
          for (int r2 = 0; r2 < 4; ++r2) {
            int o = mi * 16 + quad * 4 + r2;
            float v = acc[mi][ni][r2];
            if (ht == 0) {
              if (o < 80) out[obm + o * npx + y * W + x] = v + bias0[o];
              else if (o == 80) out[obc + y * W + x] = v + ptb[0];
            } else if (ht == 1) {
              if (o < 4) out[obm + o * npx + y * W + x] = expf((v + bias0[o]) * scv);
            } else {
              if (o < 36) out[obm + o * npx + y * W + x] = expf((v + bias0[o]) * scv);
            }
          }
        }
      }
    }
  }
}

extern "C" void kernel_launch(void* const* d_in, const int* in_sizes, int n_in,
                              void* d_out, int out_size, void* d_ws, size_t ws_size,
                              hipStream_t stream) {
  const float* feat0 = (const float*)d_in[0];
  const float* feat1 = (const float*)d_in[1];
  const float* feat2 = (const float*)d_in[2];
  const float* feat3 = (const float*)d_in[3];
  const float* feat4 = (const float*)d_in[4];
  const float* cw = (const float*)d_in[5];
  const float* rw = (const float*)d_in[8];
  const float* mw = (const float*)d_in[11];
  const float* gmas[3] = {(const float*)d_in[6], (const float*)d_in[9], (const float*)d_in[12]};
  const float* btas[3] = {(const float*)d_in[7], (const float*)d_in[10], (const float*)d_in[13]};
  const float* pcw = (const float*)d_in[14];
  const float* pcb = (const float*)d_in[15];
  const float* prw = (const float*)d_in[16];
  const float* prb = (const float*)d_in[17];
  const float* pmw = (const float*)d_in[18];
  const float* pmb = (const float*)d_in[19];
  const float* ptw = (const float*)d_in[20];
  const float* ptb = (const float*)d_in[21];
  const float* sb = (const float*)d_in[22];
  const float* sm = (const float*)d_in[23];
  float* out = (float*)d_out;

  const long ACT = 14385152;         // u16 elems per tower activation buffer
  const long ACTB = 28770304;        // bytes
  const long WTS = 14893056;         // bytes of converted weights
  char* base = (char*)d_ws;
  u16* wts = (u16*)base;

  // fused layout: wts | X3 (3) | Y3 (3) | stats (3840 B) | scaleb (30720 B) | 64 KB slack
  size_t need_fused = WTS + 6 * (size_t)ACTB + 3840 + 30720 + 65536;

  convert_weights<<<29088, 256, 0, stream>>>(cw, rw, mw, pcw, prw, pmw, ptw, wts);

  if (ws_size >= need_fused) {
    u16* X = (u16*)(base + WTS);
    u16* Y = (u16*)(base + WTS + 3 * ACTB);
    float* stats = (float*)(base + WTS + 6 * ACTB);
    float* scaleb = (float*)(base + WTS + 6 * ACTB + 3840);
    halo_zero<<<612, 256, 0, stream>>>(X, Y, ACT, 3);
    feat_to_nhwc<<<3412, 256, 0, stream>>>(feat0, feat1, feat2, feat3, feat4, X, ACT, 1);
    for (int s = 0; s < 4; ++s) {
      u16* in = (s & 1) ? Y : X;
      u16* ot = (s & 1) ? X : Y;
      long ints = (s == 0) ? 0 : ACT;  // s=0: all towers share the single staged input
      hipMemsetAsync(stats, 0, 3840, stream);
      conv_tower<<<2568, 256, 0, stream>>>(in, ints, wts + s * 589824, 4 * 589824, ot, ACT,
                                           stats, 320, scaleb, 2560, s > 0);
      finalize_stats<<<15, 256, 0, stream>>>(stats, 320,
                                             gmas[0] + s * 256, gmas[1] + s * 256, gmas[2] + s * 256,
                                             btas[0] + s * 256, btas[1] + s * 256, btas[2] + s * 256,
                                             scaleb, 2560, 3);
    }
    // s=3 raw output is in X; heads apply GN+ReLU (s=3 scaleb) during staging
    conv_head_fused<<<1284, 256, 0, stream>>>(X, ACT, -1, wts + 7077888, out,
                                              pcb, ptb, prb, pmb, sb, sm, scaleb, 2560);
  } else {
    // -------- fallback: sequential towers --------
    u16* bufA = (u16*)(base + WTS);
    u16* bufB = (u16*)(base + WTS + ACTB);
    float* stats = (float*)(base + WTS + 2 * ACTB);
    float* scaleb = (float*)(base + WTS + 2 * ACTB + 1280);
    halo_zero<<<204, 256, 0, stream>>>(bufA, bufB, 0, 1);
    for (int tw = 0; tw < 3; ++tw) {
      feat_to_nhwc<<<3412, 256, 0, stream>>>(feat0, feat1, feat2, feat3, feat4, bufA, 0, 1);
      for (int s = 0; s < 4; ++s) {
        u16* in = (s & 1) ? bufB : bufA;
        u16* ot = (s & 1) ? bufA : bufB;
        hipMemsetAsync(stats, 0, 1280, stream);
        conv_tower<<<856, 256, 0, stream>>>(in, 0, wts + (tw * 4 + s) * 589824, 0, ot, 0,
                                            stats, 0, scaleb, 0, s > 0);
        finalize_stats<<<5, 256, 0, stream>>>(stats, 0,
                                              gmas[tw] + s * 256, gmas[tw] + s * 256, gmas[tw] + s * 256,
                                              btas[tw] + s * 256, btas[tw] + s * 256, btas[tw] + s * 256,
                                              scaleb, 0, 1);
      }
      // s=3 raw output in bufA; head applies GN via scaleb (sb_ts=0)
      conv_head_fused<<<428, 256, 0, stream>>>(bufA, 0, tw, wts + 7077888, out,
                                               pcb, ptb, prb, pmb, sb, sm, scaleb, 0);
    }
  }
}